// Round 2
// baseline (3654.450 us; speedup 1.0000x reference)
//
#include <hip/hip_runtime.h>
#include <hip/hip_bf16.h>
#include <math.h>

// Shapes: B=16, C=256, H=W=96, S=3, OUT_C=64
#define NPOS 9216
#define PERB 2359296ull        // 256*9216 floats, one batch of one [C][H*W] tensor

// ---------------------------------------------------------------------------
// Positional encoding: pe[c][h*96+w], c = 4j+r
//   r==0: sin(px*f)+sin(py*f); r==1: cos+cos; r==2,3: 0.  f = exp(-2j*ln(1e4)/128)
// ---------------------------------------------------------------------------
__global__ __launch_bounds__(256) void pe_kernel(float* __restrict__ pe)
{
    int pos = blockIdx.x * 256 + threadIdx.x;  // 0..9215
    int j   = blockIdx.y;                      // 0..63
    int h = pos / 96, w = pos % 96;
    float px = (float)w * (1.0f / 95.0f);
    float py = (float)h * (1.0f / 95.0f);
    float f = expf(-(float)(2 * j) * 0.07195578415f);  // ln(10000)/128
    float ax = px * f, ay = py * f;
    float s = sinf(ax) + sinf(ay);
    float c = cosf(ax) + cosf(ay);
    size_t base = (size_t)(4 * j) * NPOS + pos;
    pe[base]            = s;
    pe[base + NPOS]     = c;
    pe[base + 2 * NPOS] = 0.0f;
    pe[base + 3 * NPOS] = 0.0f;
}

// ---------------------------------------------------------------------------
// Fused QKV GEMM. Fat M = 768 (q/k/v), N = 9216, K = 256 per (local) batch.
// Tile 128x128, 256 threads, 8x8/thread, K-step 16.
// Epilogue: q = wv*acc + qb + pe ; k = wir*acc + kb + pe ; v = wir*acc + vb
// (scale-by-weightmap commutes out of the conv since it is per-position.)
// ---------------------------------------------------------------------------
__global__ __launch_bounds__(256) void gemm_qkv(
    const float* __restrict__ srcq, const float* __restrict__ srckv,
    const float* __restrict__ qw, const float* __restrict__ kw, const float* __restrict__ vw,
    const float* __restrict__ qb, const float* __restrict__ kb, const float* __restrict__ vb,
    const float* __restrict__ wvis, const float* __restrict__ wir,
    const float* __restrict__ pe,
    float* __restrict__ qo, float* __restrict__ ko, float* __restrict__ vo)
{
    __shared__ float As[16 * 132];  // [kk][m], padded row 132
    __shared__ float Bs[16 * 128];  // [kk][n]

    int t  = threadIdx.x;
    int bm = blockIdx.x;            // 0..5
    int bn = blockIdx.y;            // 0..71
    int b  = blockIdx.z;            // local batch in group
    int mat = bm >> 1;              // 0=q,1=k,2=v
    int o0  = (bm & 1) * 128;
    int n0  = bn * 128;

    const float* A = (mat == 0) ? qw : ((mat == 1) ? kw : vw);   // [256][256]
    const float* Bsrc = ((mat == 0) ? srcq : srckv) + (size_t)b * PERB;

    int tx = t & 15, ty = t >> 4;
    float acc[8][8];
#pragma unroll
    for (int i = 0; i < 8; ++i)
#pragma unroll
        for (int j = 0; j < 8; ++j) acc[i][j] = 0.0f;

    for (int k0 = 0; k0 < 256; k0 += 16) {
#pragma unroll
        for (int l = 0; l < 2; ++l) {
            int f = t + l * 256;
            int m = f >> 2, c4 = (f & 3) * 4;
            float4 av = *(const float4*)(A + (size_t)(o0 + m) * 256 + k0 + c4);
            As[(c4 + 0) * 132 + m] = av.x;
            As[(c4 + 1) * 132 + m] = av.y;
            As[(c4 + 2) * 132 + m] = av.z;
            As[(c4 + 3) * 132 + m] = av.w;
            int c = f >> 5, n4 = (f & 31) * 4;
            *(float4*)(Bs + c * 128 + n4) =
                *(const float4*)(Bsrc + (size_t)(k0 + c) * NPOS + n0 + n4);
        }
        __syncthreads();
#pragma unroll
        for (int kk = 0; kk < 16; ++kk) {
            float a[8], bb[8];
            *(float4*)(&a[0])  = *(const float4*)(As + kk * 132 + ty * 8);
            *(float4*)(&a[4])  = *(const float4*)(As + kk * 132 + ty * 8 + 4);
            *(float4*)(&bb[0]) = *(const float4*)(Bs + kk * 128 + tx * 8);
            *(float4*)(&bb[4]) = *(const float4*)(Bs + kk * 128 + tx * 8 + 4);
#pragma unroll
            for (int i = 0; i < 8; ++i)
#pragma unroll
                for (int j = 0; j < 8; ++j)
                    acc[i][j] = fmaf(a[i], bb[j], acc[i][j]);
        }
        __syncthreads();
    }

    int n = n0 + tx * 8;
    const float* wmap = ((mat == 0) ? wvis : wir) + (size_t)b * NPOS + n;
    float sc[8];
#pragma unroll
    for (int j = 0; j < 8; ++j) sc[j] = wmap[j];

    const float* biasArr = (mat == 0) ? qb : ((mat == 1) ? kb : vb);
    float* outBase = ((mat == 0) ? qo : ((mat == 1) ? ko : vo)) + (size_t)b * PERB;

#pragma unroll
    for (int i = 0; i < 8; ++i) {
        int o = o0 + ty * 8 + i;
        float bias = biasArr[o];
        float vals[8];
        if (mat != 2) {
            const float* per = pe + (size_t)o * NPOS + n;
#pragma unroll
            for (int j = 0; j < 8; ++j) vals[j] = fmaf(acc[i][j], sc[j], bias + per[j]);
        } else {
#pragma unroll
            for (int j = 0; j < 8; ++j) vals[j] = fmaf(acc[i][j], sc[j], bias);
        }
        float* op = outBase + (size_t)o * NPOS + n;
        *(float4*)(op)     = *(float4*)(&vals[0]);
        *(float4*)(op + 4) = *(float4*)(&vals[4]);
    }
}

// ---------------------------------------------------------------------------
// Attention per (b,c): logits = Q K^T (96x96), softmax over g, fused = attn V.
// One block (256 thr) per plane; q,k,v staged in LDS (pad 100); 6x6 reg tiles.
// ---------------------------------------------------------------------------
__global__ __launch_bounds__(256) void attn_kernel(
    const float* __restrict__ q, const float* __restrict__ k,
    const float* __restrict__ v, float* __restrict__ fused)
{
    __shared__ float qs[96 * 100];  // reused for attn matrix
    __shared__ float ks[96 * 100];
    __shared__ float vs[96 * 100];

    int t  = threadIdx.x;
    int bc = blockIdx.x;                     // lb*256 + c
    const size_t base = (size_t)bc * NPOS;

    for (int f = t; f < 96 * 24; f += 256) {
        int r = f / 24, w4 = (f % 24) * 4;
        *(float4*)(qs + r * 100 + w4) = *(const float4*)(q + base + r * 96 + w4);
        *(float4*)(ks + r * 100 + w4) = *(const float4*)(k + base + r * 96 + w4);
        *(float4*)(vs + r * 100 + w4) = *(const float4*)(v + base + r * 96 + w4);
    }
    __syncthreads();

    int tx = t & 15, ty = t >> 4;
    int h0 = ty * 6, g0 = tx * 6;

    float acc[6][6];
#pragma unroll
    for (int i = 0; i < 6; ++i)
#pragma unroll
        for (int j = 0; j < 6; ++j) acc[i][j] = 0.0f;

    for (int w4 = 0; w4 < 24; ++w4) {
        float4 qv[6], kv[6];
#pragma unroll
        for (int i = 0; i < 6; ++i) qv[i] = *(const float4*)(qs + (h0 + i) * 100 + w4 * 4);
#pragma unroll
        for (int j = 0; j < 6; ++j) kv[j] = *(const float4*)(ks + (g0 + j) * 100 + w4 * 4);
#pragma unroll
        for (int i = 0; i < 6; ++i)
#pragma unroll
            for (int j = 0; j < 6; ++j) {
                acc[i][j] = fmaf(qv[i].x, kv[j].x, acc[i][j]);
                acc[i][j] = fmaf(qv[i].y, kv[j].y, acc[i][j]);
                acc[i][j] = fmaf(qv[i].z, kv[j].z, acc[i][j]);
                acc[i][j] = fmaf(qv[i].w, kv[j].w, acc[i][j]);
            }
    }

    // softmax along g (16 lanes of same ty own one row; wave-internal shuffle)
#pragma unroll
    for (int i = 0; i < 6; ++i) {
        float m = acc[i][0];
#pragma unroll
        for (int j = 1; j < 6; ++j) m = fmaxf(m, acc[i][j]);
        for (int d = 1; d < 16; d <<= 1) m = fmaxf(m, __shfl_xor(m, d));
        float s = 0.0f;
#pragma unroll
        for (int j = 0; j < 6; ++j) {
            acc[i][j] = expf(acc[i][j] - m);   // accurate expf (precision)
            s += acc[i][j];
        }
        for (int d = 1; d < 16; d <<= 1) s += __shfl_xor(s, d);
        float inv = 1.0f / s;
#pragma unroll
        for (int j = 0; j < 6; ++j) acc[i][j] *= inv;
    }

    __syncthreads();
#pragma unroll
    for (int i = 0; i < 6; ++i)
#pragma unroll
        for (int j = 0; j < 6; ++j) qs[(h0 + i) * 100 + g0 + j] = acc[i][j];
    __syncthreads();

    int w0 = tx * 6;
    float outv[6][6];
#pragma unroll
    for (int i = 0; i < 6; ++i)
#pragma unroll
        for (int j = 0; j < 6; ++j) outv[i][j] = 0.0f;

    for (int g4 = 0; g4 < 24; ++g4) {
        float4 av[6];
#pragma unroll
        for (int i = 0; i < 6; ++i) av[i] = *(const float4*)(qs + (h0 + i) * 100 + g4 * 4);
#pragma unroll
        for (int gg = 0; gg < 4; ++gg) {
            int g = g4 * 4 + gg;
            float vr[6];
#pragma unroll
            for (int j = 0; j < 6; ++j) vr[j] = vs[g * 100 + w0 + j];
#pragma unroll
            for (int i = 0; i < 6; ++i) {
                float a = (gg == 0) ? av[i].x : (gg == 1) ? av[i].y : (gg == 2) ? av[i].z : av[i].w;
#pragma unroll
                for (int j = 0; j < 6; ++j) outv[i][j] = fmaf(a, vr[j], outv[i][j]);
            }
        }
    }

#pragma unroll
    for (int i = 0; i < 6; ++i) {
        float* op = fused + base + (size_t)(h0 + i) * 96 + w0;
#pragma unroll
        for (int j = 0; j < 6; ++j) op[j] = outv[i][j];
    }
}

// ---------------------------------------------------------------------------
// Final projection: out[b][o][n] = sum_c proj_w[o][c]*fused[b][c][n] + pb[o]
// ---------------------------------------------------------------------------
__global__ __launch_bounds__(256) void proj_kernel(
    const float* __restrict__ fused, const float* __restrict__ pw,
    const float* __restrict__ pb, float* __restrict__ out)
{
    __shared__ float As[16 * 68];
    __shared__ float Bs[16 * 128];

    int t  = threadIdx.x;
    int n0 = blockIdx.x * 128;
    int b  = blockIdx.y;            // local batch in group
    const float* B = fused + (size_t)b * PERB;
    int tx = t & 15, ty = t >> 4;

    float acc[4][8];
#pragma unroll
    for (int i = 0; i < 4; ++i)
#pragma unroll
        for (int j = 0; j < 8; ++j) acc[i][j] = 0.0f;

    for (int k0 = 0; k0 < 256; k0 += 16) {
        {
            int m = t >> 2, c4 = (t & 3) * 4;
            float4 av = *(const float4*)(pw + (size_t)m * 256 + k0 + c4);
            As[(c4 + 0) * 68 + m] = av.x;
            As[(c4 + 1) * 68 + m] = av.y;
            As[(c4 + 2) * 68 + m] = av.z;
            As[(c4 + 3) * 68 + m] = av.w;
        }
#pragma unroll
        for (int l = 0; l < 2; ++l) {
            int f = t + l * 256;
            int c = f >> 5, n4 = (f & 31) * 4;
            *(float4*)(Bs + c * 128 + n4) =
                *(const float4*)(B + (size_t)(k0 + c) * NPOS + n0 + n4);
        }
        __syncthreads();
#pragma unroll
        for (int kk = 0; kk < 16; ++kk) {
            float a[4], bb[8];
            *(float4*)(&a[0])  = *(const float4*)(As + kk * 68 + ty * 4);
            *(float4*)(&bb[0]) = *(const float4*)(Bs + kk * 128 + tx * 8);
            *(float4*)(&bb[4]) = *(const float4*)(Bs + kk * 128 + tx * 8 + 4);
#pragma unroll
            for (int i = 0; i < 4; ++i)
#pragma unroll
                for (int j = 0; j < 8; ++j)
                    acc[i][j] = fmaf(a[i], bb[j], acc[i][j]);
        }
        __syncthreads();
    }

    int n = n0 + tx * 8;
#pragma unroll
    for (int i = 0; i < 4; ++i) {
        int o = ty * 4 + i;
        float bias = pb[o];
        float vals[8];
#pragma unroll
        for (int j = 0; j < 8; ++j) vals[j] = acc[i][j] + bias;
        float* op = out + ((size_t)b * 64 + o) * NPOS + n;
        *(float4*)(op)     = *(float4*)(&vals[0]);
        *(float4*)(op + 4) = *(float4*)(&vals[4]);
    }
}

// ---------------------------------------------------------------------------
extern "C" void kernel_launch(void* const* d_in, const int* in_sizes, int n_in,
                              void* d_out, int out_size, void* d_ws, size_t ws_size,
                              hipStream_t stream)
{
    const float* x1   = (const float*)d_in[0];
    const float* x2   = (const float*)d_in[1];
    const float* wvis = (const float*)d_in[2];
    const float* wir  = (const float*)d_in[3];
    const float* qw   = (const float*)d_in[4];
    const float* qb   = (const float*)d_in[5];
    const float* kw   = (const float*)d_in[6];
    const float* kb   = (const float*)d_in[7];
    const float* vw   = (const float*)d_in[8];
    const float* vb   = (const float*)d_in[9];
    const float* pw   = (const float*)d_in[10];
    const float* pb   = (const float*)d_in[11];
    float* out = (float*)d_out;

    // Batch-group size G chosen from ws_size (deterministic): per-group
    // footprint = (4*G + 1) * PERB floats.  G=1 needs ~47 MB.
    float* ws = (float*)d_ws;
    size_t Ffloats = ws_size / 4;
    size_t avail = (Ffloats > PERB) ? (Ffloats - PERB) : 0;
    int G = (int)(avail / (4 * PERB));
    if (G < 1) G = 1;
    if (G > 8) G = 8;

    float* pebuf = ws;
    float* qbuf  = ws + PERB;
    float* kbuf  = qbuf + (size_t)G * PERB;
    float* vbuf  = kbuf + (size_t)G * PERB;
    float* fbuf  = vbuf + (size_t)G * PERB;

    pe_kernel<<<dim3(36, 64), 256, 0, stream>>>(pebuf);

    for (int b0 = 0; b0 < 16; b0 += G) {
        int g = (16 - b0 < G) ? (16 - b0) : G;
        for (int s = 0; s < 3; ++s) {
            const float* sq  = (s == 0) ? (x1 + (size_t)b0 * PERB) : fbuf;
            const float* skv = (s == 0) ? (x2 + (size_t)b0 * PERB) : fbuf;
            gemm_qkv<<<dim3(6, 72, g), 256, 0, stream>>>(
                sq, skv,
                qw + (size_t)s * 65536, kw + (size_t)s * 65536, vw + (size_t)s * 65536,
                qb + (size_t)s * 256,   kb + (size_t)s * 256,   vb + (size_t)s * 256,
                wvis + (size_t)b0 * NPOS, wir + (size_t)b0 * NPOS,
                pebuf, qbuf, kbuf, vbuf);
            attn_kernel<<<dim3(256 * g), 256, 0, stream>>>(qbuf, kbuf, vbuf, fbuf);
        }
        proj_kernel<<<dim3(72, g), 256, 0, stream>>>(
            fbuf, pw, pb, out + (size_t)b0 * 64 * NPOS);
    }
}

// Round 3
// 2843.359 us; speedup vs baseline: 1.2853x; 1.2853x over previous
//
#include <hip/hip_runtime.h>
#include <hip/hip_bf16.h>
#include <math.h>

// Shapes: B=16, C=256, H=W=96, S=3, OUT_C=64
#define NPOS 9216
#define PERB 2359296ull        // 256*9216 elements (one [C][H*W] plane-set)

typedef unsigned short u16;
typedef __attribute__((ext_vector_type(8))) short short8;  // bf16x8 MFMA frag
typedef __attribute__((ext_vector_type(4))) float f32x4;   // MFMA acc

__device__ inline u16 bfhi(float x) {
    unsigned int b = __float_as_uint(x);
    return (u16)((b + 0x7FFFu + ((b >> 16) & 1u)) >> 16);   // RNE f32->bf16
}
__device__ inline float bf2f(u16 u) { return __uint_as_float(((unsigned int)u) << 16); }

// ---------------------------------------------------------------------------
// Positional encoding: pe[c][h*96+w], c=4j+r: r0=sin+sin, r1=cos+cos, r2/3=0
// ---------------------------------------------------------------------------
__global__ __launch_bounds__(256) void pe_kernel(float* __restrict__ pe)
{
    int pos = blockIdx.x * 256 + threadIdx.x;  // 0..9215
    int j   = blockIdx.y;                      // 0..63
    int h = pos / 96, w = pos % 96;
    float px = (float)w * (1.0f / 95.0f);
    float py = (float)h * (1.0f / 95.0f);
    float f = expf(-(float)(2 * j) * 0.07195578415f);  // ln(10000)/128
    float ax = px * f, ay = py * f;
    float s = sinf(ax) + sinf(ay);
    float c = cosf(ax) + cosf(ay);
    size_t base = (size_t)(4 * j) * NPOS + pos;
    pe[base]            = s;
    pe[base + NPOS]     = c;
    pe[base + 2 * NPOS] = 0.0f;
    pe[base + 3 * NPOS] = 0.0f;
}

// ---------------------------------------------------------------------------
// Weight split: W[s][mat][256][256] f32 -> blocked bf16 hi/lo
// layout: [s][mat*2+mb][kb][128][32]  (k-contiguous rows, no transpose needed)
// grid 144 = s(3) x mat(3) x mb(2) x kb(8), 256 thr
// ---------------------------------------------------------------------------
__global__ __launch_bounds__(256) void wsplit(
    const float* __restrict__ qw, const float* __restrict__ kw,
    const float* __restrict__ vw, u16* __restrict__ whi, u16* __restrict__ wlo)
{
    int bid = blockIdx.x;
    int s = bid / 48, rem = bid % 48;
    int mat = rem / 16, rem2 = rem % 16;
    int mb = rem2 / 8, kb = rem2 % 8;
    const float* W = ((mat == 0) ? qw : (mat == 1) ? kw : vw) + (size_t)s * 65536;
    int t = threadIdx.x;
    int m = t >> 1, kh = (t & 1) * 16;
    const float* src = W + (size_t)(mb * 128 + m) * 256 + kb * 32 + kh;
    size_t ob = (size_t)s * 196608 + (size_t)((mat * 2 + mb) * 8 + kb) * 4096
              + (size_t)m * 32 + kh;
    u16 hv[16], lv[16];
#pragma unroll
    for (int j = 0; j < 16; ++j) {
        float x = src[j];
        u16 h = bfhi(x);
        hv[j] = h;
        lv[j] = bfhi(x - bf2f(h));
    }
    *(uint4*)(whi + ob)     = *(uint4*)hv;
    *(uint4*)(whi + ob + 8) = *(uint4*)(hv + 8);
    *(uint4*)(wlo + ob)     = *(uint4*)lv;
    *(uint4*)(wlo + ob + 8) = *(uint4*)(lv + 8);
}

// ---------------------------------------------------------------------------
// Input split+transpose: src[b][256][9216] f32 -> blocked bf16 hi/lo
// layout per batch: [tau=nb*8+kb][128 n][32 k]  (n-major rows, k-contiguous)
// grid (576, g), 256 thr; LDS-transposed 32x128 tiles.
// ---------------------------------------------------------------------------
__global__ __launch_bounds__(256) void splitcvt(
    const float* __restrict__ src, u16* __restrict__ hi, u16* __restrict__ lo)
{
    __shared__ float ls[32 * 132];
    int tau = blockIdx.x;          // 0..575
    int nb = tau >> 3, kb = tau & 7;
    int b = blockIdx.y;
    const float* in = src + (size_t)b * PERB + (size_t)(kb * 32) * NPOS + nb * 128;
    int t = threadIdx.x;
#pragma unroll
    for (int i = 0; i < 4; ++i) {
        int idx = i * 256 + t;
        int r = idx >> 5, nq = (idx & 31) * 4;
        *(float4*)&ls[r * 132 + nq] = *(const float4*)&in[(size_t)r * NPOS + nq];
    }
    __syncthreads();
    int n = t >> 1, kh = (t & 1) * 16;
    size_t ob = (size_t)b * PERB + (size_t)tau * 4096 + (size_t)n * 32 + kh;
    u16 hv[16], lv[16];
#pragma unroll
    for (int j = 0; j < 16; ++j) {
        float x = ls[(kh + j) * 132 + n];   // col read: banks (4k+n)%32... pad132 ok
        u16 h = bfhi(x);
        hv[j] = h;
        lv[j] = bfhi(x - bf2f(h));
    }
    *(uint4*)(hi + ob)     = *(uint4*)hv;
    *(uint4*)(hi + ob + 8) = *(uint4*)(hv + 8);
    *(uint4*)(lo + ob)     = *(uint4*)lv;
    *(uint4*)(lo + ob + 8) = *(uint4*)(lv + 8);
}

// ---------------------------------------------------------------------------
// MFMA QKV GEMM, split-bf16 (hi/lo, 3 MFMA per product term).
// Fat M=768 (q/k/v x 2 mtiles), N=9216, K=256. Tile 128x128, BK=32, 4 waves.
// Epilogue: q = sc*acc + qb + pe ; k = sc*acc + kb + pe ; v = sc*acc + vb
// ---------------------------------------------------------------------------
__global__ __launch_bounds__(256) void gemm_qkv_mfma(
    const u16* __restrict__ whi, const u16* __restrict__ wlo,     // stage base
    const u16* __restrict__ b1hi, const u16* __restrict__ b1lo,   // src for q
    const u16* __restrict__ b2hi, const u16* __restrict__ b2lo,   // src for k,v
    const float* __restrict__ qb, const float* __restrict__ kbias,
    const float* __restrict__ vb, const float* __restrict__ wvis,
    const float* __restrict__ wir, const float* __restrict__ pe,
    float* __restrict__ qo, float* __restrict__ ko, float* __restrict__ vo)
{
    __shared__ u16 Ah[4096], Al[4096], Bh[4096], Bl[4096];  // 4 x 8KB
    int t = threadIdx.x, lane = t & 63;
    int bm = blockIdx.x, bn = blockIdx.y, b = blockIdx.z;
    int mat = bm >> 1, mtile = bm & 1;
    const u16* gBh = ((mat == 0) ? b1hi : b2hi) + (size_t)b * PERB + (size_t)bn * 32768;
    const u16* gBl = ((mat == 0) ? b1lo : b2lo) + (size_t)b * PERB + (size_t)bn * 32768;
    const u16* gAh = whi + (size_t)(mat * 2 + mtile) * 32768;
    const u16* gAl = wlo + (size_t)(mat * 2 + mtile) * 32768;
    int wv = t >> 6, wm = wv >> 1, wn = wv & 1;
    int rr = lane & 15, gq = lane >> 4;

    f32x4 acc[4][4];
#pragma unroll
    for (int i = 0; i < 4; ++i)
#pragma unroll
        for (int j = 0; j < 4; ++j) acc[i][j] = (f32x4){0.f, 0.f, 0.f, 0.f};

    for (int kq = 0; kq < 8; ++kq) {
        const uint4* sah = (const uint4*)(gAh + kq * 4096);
        const uint4* sal = (const uint4*)(gAl + kq * 4096);
        const uint4* sbh = (const uint4*)(gBh + kq * 4096);
        const uint4* sbl = (const uint4*)(gBl + kq * 4096);
        uint4 va0 = sah[t], va1 = sah[t + 256];
        uint4 vb0 = sal[t], vb1 = sal[t + 256];
        uint4 vc0 = sbh[t], vc1 = sbh[t + 256];
        uint4 vd0 = sbl[t], vd1 = sbl[t + 256];
        __syncthreads();             // prior compute done reading LDS
        ((uint4*)Ah)[t] = va0; ((uint4*)Ah)[t + 256] = va1;
        ((uint4*)Al)[t] = vb0; ((uint4*)Al)[t + 256] = vb1;
        ((uint4*)Bh)[t] = vc0; ((uint4*)Bh)[t + 256] = vc1;
        ((uint4*)Bl)[t] = vd0; ((uint4*)Bl)[t + 256] = vd1;
        __syncthreads();

        short8 ah[4], al[4], bh[4], bl[4];
#pragma unroll
        for (int f = 0; f < 4; ++f) {
            int ro = (wm * 64 + f * 16 + rr) * 32 + gq * 8;
            ah[f] = *(const short8*)(Ah + ro);
            al[f] = *(const short8*)(Al + ro);
        }
#pragma unroll
        for (int r = 0; r < 4; ++r) {
            int ro = (wn * 64 + r * 16 + rr) * 32 + gq * 8;
            bh[r] = *(const short8*)(Bh + ro);
            bl[r] = *(const short8*)(Bl + ro);
        }
#pragma unroll
        for (int f = 0; f < 4; ++f)
#pragma unroll
            for (int r = 0; r < 4; ++r) {
                acc[f][r] = __builtin_amdgcn_mfma_f32_16x16x32_bf16(ah[f], bh[r], acc[f][r], 0, 0, 0);
                acc[f][r] = __builtin_amdgcn_mfma_f32_16x16x32_bf16(ah[f], bl[r], acc[f][r], 0, 0, 0);
                acc[f][r] = __builtin_amdgcn_mfma_f32_16x16x32_bf16(al[f], bh[r], acc[f][r], 0, 0, 0);
            }
    }

    const float* wmap = ((mat == 0) ? wvis : wir) + (size_t)b * NPOS;
    const float* bias = (mat == 0) ? qb : (mat == 1) ? kbias : vb;
    float* outp = ((mat == 0) ? qo : (mat == 1) ? ko : vo) + (size_t)b * PERB;
    bool addpe = (mat != 2);
#pragma unroll
    for (int r = 0; r < 4; ++r) {
        int n = bn * 128 + wn * 64 + r * 16 + rr;
        float sc = wmap[n];
#pragma unroll
        for (int f = 0; f < 4; ++f)
#pragma unroll
            for (int ri = 0; ri < 4; ++ri) {
                int o = mtile * 128 + wm * 64 + f * 16 + gq * 4 + ri;  // D row=(l>>4)*4+reg
                float vvv = acc[f][r][ri] * sc + bias[o];
                if (addpe) vvv += pe[(size_t)o * NPOS + n];
                outp[(size_t)o * NPOS + n] = vvv;
            }
    }
}

// ---------------------------------------------------------------------------
// Attention per (b,c): logits = Q K^T (96x96), softmax, fused = attn V. (f32)
// ---------------------------------------------------------------------------
__global__ __launch_bounds__(256) void attn_kernel(
    const float* __restrict__ q, const float* __restrict__ k,
    const float* __restrict__ v, float* __restrict__ fused)
{
    __shared__ float qs[96 * 100];  // reused for attn matrix
    __shared__ float ks[96 * 100];
    __shared__ float vs[96 * 100];

    int t  = threadIdx.x;
    int bc = blockIdx.x;
    const size_t base = (size_t)bc * NPOS;

    for (int f = t; f < 96 * 24; f += 256) {
        int r = f / 24, w4 = (f % 24) * 4;
        *(float4*)(qs + r * 100 + w4) = *(const float4*)(q + base + r * 96 + w4);
        *(float4*)(ks + r * 100 + w4) = *(const float4*)(k + base + r * 96 + w4);
        *(float4*)(vs + r * 100 + w4) = *(const float4*)(v + base + r * 96 + w4);
    }
    __syncthreads();

    int tx = t & 15, ty = t >> 4;
    int h0 = ty * 6, g0 = tx * 6;

    float acc[6][6];
#pragma unroll
    for (int i = 0; i < 6; ++i)
#pragma unroll
        for (int j = 0; j < 6; ++j) acc[i][j] = 0.0f;

    for (int w4 = 0; w4 < 24; ++w4) {
        float4 qv[6], kv[6];
#pragma unroll
        for (int i = 0; i < 6; ++i) qv[i] = *(const float4*)(qs + (h0 + i) * 100 + w4 * 4);
#pragma unroll
        for (int j = 0; j < 6; ++j) kv[j] = *(const float4*)(ks + (g0 + j) * 100 + w4 * 4);
#pragma unroll
        for (int i = 0; i < 6; ++i)
#pragma unroll
            for (int j = 0; j < 6; ++j) {
                acc[i][j] = fmaf(qv[i].x, kv[j].x, acc[i][j]);
                acc[i][j] = fmaf(qv[i].y, kv[j].y, acc[i][j]);
                acc[i][j] = fmaf(qv[i].z, kv[j].z, acc[i][j]);
                acc[i][j] = fmaf(qv[i].w, kv[j].w, acc[i][j]);
            }
    }

#pragma unroll
    for (int i = 0; i < 6; ++i) {
        float m = acc[i][0];
#pragma unroll
        for (int j = 1; j < 6; ++j) m = fmaxf(m, acc[i][j]);
        for (int d = 1; d < 16; d <<= 1) m = fmaxf(m, __shfl_xor(m, d));
        float s = 0.0f;
#pragma unroll
        for (int j = 0; j < 6; ++j) {
            acc[i][j] = expf(acc[i][j] - m);
            s += acc[i][j];
        }
        for (int d = 1; d < 16; d <<= 1) s += __shfl_xor(s, d);
        float inv = 1.0f / s;
#pragma unroll
        for (int j = 0; j < 6; ++j) acc[i][j] *= inv;
    }

    __syncthreads();
#pragma unroll
    for (int i = 0; i < 6; ++i)
#pragma unroll
        for (int j = 0; j < 6; ++j) qs[(h0 + i) * 100 + g0 + j] = acc[i][j];
    __syncthreads();

    int w0 = tx * 6;
    float outv[6][6];
#pragma unroll
    for (int i = 0; i < 6; ++i)
#pragma unroll
        for (int j = 0; j < 6; ++j) outv[i][j] = 0.0f;

    for (int g4 = 0; g4 < 24; ++g4) {
        float4 av[6];
#pragma unroll
        for (int i = 0; i < 6; ++i) av[i] = *(const float4*)(qs + (h0 + i) * 100 + g4 * 4);
#pragma unroll
        for (int gg = 0; gg < 4; ++gg) {
            int g = g4 * 4 + gg;
            float vr[6];
#pragma unroll
            for (int j = 0; j < 6; ++j) vr[j] = vs[g * 100 + w0 + j];
#pragma unroll
            for (int i = 0; i < 6; ++i) {
                float a = (gg == 0) ? av[i].x : (gg == 1) ? av[i].y : (gg == 2) ? av[i].z : av[i].w;
#pragma unroll
                for (int j = 0; j < 6; ++j) outv[i][j] = fmaf(a, vr[j], outv[i][j]);
            }
        }
    }

#pragma unroll
    for (int i = 0; i < 6; ++i) {
        float* op = fused + base + (size_t)(h0 + i) * 96 + w0;
#pragma unroll
        for (int j = 0; j < 6; ++j) op[j] = outv[i][j];
    }
}

// ---------------------------------------------------------------------------
// Final projection: out[b][o][n] = sum_c proj_w[o][c]*fused[b][c][n] + pb[o]
// ---------------------------------------------------------------------------
__global__ __launch_bounds__(256) void proj_kernel(
    const float* __restrict__ fused, const float* __restrict__ pw,
    const float* __restrict__ pb, float* __restrict__ out)
{
    __shared__ float As[16 * 68];
    __shared__ float Bs[16 * 128];

    int t  = threadIdx.x;
    int n0 = blockIdx.x * 128;
    int b  = blockIdx.y;
    const float* B = fused + (size_t)b * PERB;
    int tx = t & 15, ty = t >> 4;

    float acc[4][8];
#pragma unroll
    for (int i = 0; i < 4; ++i)
#pragma unroll
        for (int j = 0; j < 8; ++j) acc[i][j] = 0.0f;

    for (int k0 = 0; k0 < 256; k0 += 16) {
        {
            int m = t >> 2, c4 = (t & 3) * 4;
            float4 av = *(const float4*)(pw + (size_t)m * 256 + k0 + c4);
            As[(c4 + 0) * 68 + m] = av.x;
            As[(c4 + 1) * 68 + m] = av.y;
            As[(c4 + 2) * 68 + m] = av.z;
            As[(c4 + 3) * 68 + m] = av.w;
        }
#pragma unroll
        for (int l = 0; l < 2; ++l) {
            int f = t + l * 256;
            int c = f >> 5, n4 = (f & 31) * 4;
            *(float4*)(Bs + c * 128 + n4) =
                *(const float4*)(B + (size_t)(k0 + c) * NPOS + n0 + n4);
        }
        __syncthreads();
#pragma unroll
        for (int kk = 0; kk < 16; ++kk) {
            float a[4], bb[8];
            *(float4*)(&a[0])  = *(const float4*)(As + kk * 68 + ty * 4);
            *(float4*)(&bb[0]) = *(const float4*)(Bs + kk * 128 + tx * 8);
            *(float4*)(&bb[4]) = *(const float4*)(Bs + kk * 128 + tx * 8 + 4);
#pragma unroll
            for (int i = 0; i < 4; ++i)
#pragma unroll
                for (int j = 0; j < 8; ++j)
                    acc[i][j] = fmaf(a[i], bb[j], acc[i][j]);
        }
        __syncthreads();
    }

    int n = n0 + tx * 8;
#pragma unroll
    for (int i = 0; i < 4; ++i) {
        int o = ty * 4 + i;
        float bias = pb[o];
        float vals[8];
#pragma unroll
        for (int j = 0; j < 8; ++j) vals[j] = acc[i][j] + bias;
        float* op = out + ((size_t)b * 64 + o) * NPOS + n;
        *(float4*)(op)     = *(float4*)(&vals[0]);
        *(float4*)(op + 4) = *(float4*)(&vals[4]);
    }
}

// ---------------------------------------------------------------------------
extern "C" void kernel_launch(void* const* d_in, const int* in_sizes, int n_in,
                              void* d_out, int out_size, void* d_ws, size_t ws_size,
                              hipStream_t stream)
{
    const float* x1   = (const float*)d_in[0];
    const float* x2   = (const float*)d_in[1];
    const float* wvis = (const float*)d_in[2];
    const float* wir  = (const float*)d_in[3];
    const float* qw   = (const float*)d_in[4];
    const float* qb   = (const float*)d_in[5];
    const float* kw   = (const float*)d_in[6];
    const float* kb   = (const float*)d_in[7];
    const float* vw   = (const float*)d_in[8];
    const float* vb   = (const float*)d_in[9];
    const float* pw   = (const float*)d_in[10];
    const float* pb   = (const float*)d_in[11];
    float* out = (float*)d_out;

    // ws budget (floats): pe(PERB) + weights(~0.6M) + G*(4 f32 bufs + 2 f32-equiv bf16 bufs)*PERB
    float* ws = (float*)d_ws;
    size_t F = ws_size / 4;
    size_t fixed = PERB + 600000;
    size_t avail = (F > fixed) ? (F - fixed) : 0;
    int G = (int)(avail / (6 * PERB));
    if (G < 1) G = 1;
    if (G > 8) G = 8;

    float* pebuf = ws;
    float* qbuf  = ws + PERB;
    float* kbuf  = qbuf + (size_t)G * PERB;
    float* vbuf  = kbuf + (size_t)G * PERB;
    float* fbuf  = vbuf + (size_t)G * PERB;
    u16*   b1hi  = (u16*)(fbuf + (size_t)G * PERB);
    u16*   b1lo  = b1hi + (size_t)G * PERB;
    u16*   b2hi  = b1lo + (size_t)G * PERB;
    u16*   b2lo  = b2hi + (size_t)G * PERB;
    u16*   whiP  = b2lo + (size_t)G * PERB;
    u16*   wloP  = whiP + 589824;

    pe_kernel<<<dim3(36, 64), 256, 0, stream>>>(pebuf);
    wsplit<<<dim3(144), 256, 0, stream>>>(qw, kw, vw, whiP, wloP);

    for (int b0 = 0; b0 < 16; b0 += G) {
        int g = (16 - b0 < G) ? (16 - b0) : G;
        splitcvt<<<dim3(576, g), 256, 0, stream>>>(x1 + (size_t)b0 * PERB, b1hi, b1lo);
        splitcvt<<<dim3(576, g), 256, 0, stream>>>(x2 + (size_t)b0 * PERB, b2hi, b2lo);
        for (int s = 0; s < 3; ++s) {
            if (s > 0)
                splitcvt<<<dim3(576, g), 256, 0, stream>>>(fbuf, b1hi, b1lo);
            const u16* xh = (s == 0) ? b2hi : b1hi;
            const u16* xl = (s == 0) ? b2lo : b1lo;
            gemm_qkv_mfma<<<dim3(6, 72, g), 256, 0, stream>>>(
                whiP + (size_t)s * 196608, wloP + (size_t)s * 196608,
                b1hi, b1lo, xh, xl,
                qb + (size_t)s * 256, kb + (size_t)s * 256, vb + (size_t)s * 256,
                wvis + (size_t)b0 * NPOS, wir + (size_t)b0 * NPOS,
                pebuf, qbuf, kbuf, vbuf);
            attn_kernel<<<dim3(256 * g), 256, 0, stream>>>(qbuf, kbuf, vbuf, fbuf);
        }
        proj_kernel<<<dim3(72, g), 256, 0, stream>>>(
            fbuf, pw, pb, out + (size_t)b0 * 64 * NPOS);
    }
}

// Round 4
// 2587.572 us; speedup vs baseline: 1.4123x; 1.0989x over previous
//
#include <hip/hip_runtime.h>
#include <hip/hip_bf16.h>
#include <math.h>

// Shapes: B=16, C=256, H=W=96, S=3, OUT_C=64
#define NPOS 9216
#define PERB 2359296ull        // 256*9216 elements (one [C][H*W] plane-set)

typedef unsigned short u16;
typedef __attribute__((ext_vector_type(8))) short short8;  // bf16x8 MFMA frag
typedef __attribute__((ext_vector_type(4))) float f32x4;   // MFMA acc

__device__ inline u16 bfhi(float x) {
    unsigned int b = __float_as_uint(x);
    return (u16)((b + 0x7FFFu + ((b >> 16) & 1u)) >> 16);   // RNE f32->bf16
}
__device__ inline float bf2f(u16 u) { return __uint_as_float(((unsigned int)u) << 16); }

// ---------------------------------------------------------------------------
// Positional encoding: pe[c][h*96+w], c=4j+r: r0=sin+sin, r1=cos+cos, r2/3=0
// ---------------------------------------------------------------------------
__global__ __launch_bounds__(256) void pe_kernel(float* __restrict__ pe)
{
    int pos = blockIdx.x * 256 + threadIdx.x;  // 0..9215
    int j   = blockIdx.y;                      // 0..63
    int h = pos / 96, w = pos % 96;
    float px = (float)w * (1.0f / 95.0f);
    float py = (float)h * (1.0f / 95.0f);
    float f = expf(-(float)(2 * j) * 0.07195578415f);  // ln(10000)/128
    float ax = px * f, ay = py * f;
    float s = sinf(ax) + sinf(ay);
    float c = cosf(ax) + cosf(ay);
    size_t base = (size_t)(4 * j) * NPOS + pos;
    pe[base]            = s;
    pe[base + NPOS]     = c;
    pe[base + 2 * NPOS] = 0.0f;
    pe[base + 3 * NPOS] = 0.0f;
}

// ---------------------------------------------------------------------------
// Weight split: W[s][mat][256][256] f32 -> blocked bf16 hi/lo
// layout: [s][mat*2+mb][kb][128][32]  (k-contiguous rows)
// ---------------------------------------------------------------------------
__global__ __launch_bounds__(256) void wsplit(
    const float* __restrict__ qw, const float* __restrict__ kw,
    const float* __restrict__ vw, u16* __restrict__ whi, u16* __restrict__ wlo)
{
    int bid = blockIdx.x;
    int s = bid / 48, rem = bid % 48;
    int mat = rem / 16, rem2 = rem % 16;
    int mb = rem2 / 8, kb = rem2 % 8;
    const float* W = ((mat == 0) ? qw : (mat == 1) ? kw : vw) + (size_t)s * 65536;
    int t = threadIdx.x;
    int m = t >> 1, kh = (t & 1) * 16;
    const float* src = W + (size_t)(mb * 128 + m) * 256 + kb * 32 + kh;
    size_t ob = (size_t)s * 196608 + (size_t)((mat * 2 + mb) * 8 + kb) * 4096
              + (size_t)m * 32 + kh;
    u16 hv[16], lv[16];
#pragma unroll
    for (int j = 0; j < 16; ++j) {
        float x = src[j];
        u16 h = bfhi(x);
        hv[j] = h;
        lv[j] = bfhi(x - bf2f(h));
    }
    *(uint4*)(whi + ob)     = *(uint4*)hv;
    *(uint4*)(whi + ob + 8) = *(uint4*)(hv + 8);
    *(uint4*)(wlo + ob)     = *(uint4*)lv;
    *(uint4*)(wlo + ob + 8) = *(uint4*)(lv + 8);
}

// ---------------------------------------------------------------------------
// Input split+transpose: src[b][256][9216] f32 -> blocked bf16 hi/lo
// layout per batch: [tau=nb*8+kb][128 n][32 k]
// ---------------------------------------------------------------------------
__global__ __launch_bounds__(256) void splitcvt(
    const float* __restrict__ src, u16* __restrict__ hi, u16* __restrict__ lo)
{
    __shared__ float ls[32 * 132];
    int tau = blockIdx.x;          // 0..575
    int nb = tau >> 3, kb = tau & 7;
    int b = blockIdx.y;
    const float* in = src + (size_t)b * PERB + (size_t)(kb * 32) * NPOS + nb * 128;
    int t = threadIdx.x;
#pragma unroll
    for (int i = 0; i < 4; ++i) {
        int idx = i * 256 + t;
        int r = idx >> 5, nq = (idx & 31) * 4;
        *(float4*)&ls[r * 132 + nq] = *(const float4*)&in[(size_t)r * NPOS + nq];
    }
    __syncthreads();
    int n = t >> 1, kh = (t & 1) * 16;
    size_t ob = (size_t)b * PERB + (size_t)tau * 4096 + (size_t)n * 32 + kh;
    u16 hv[16], lv[16];
#pragma unroll
    for (int j = 0; j < 16; ++j) {
        float x = ls[(kh + j) * 132 + n];
        u16 h = bfhi(x);
        hv[j] = h;
        lv[j] = bfhi(x - bf2f(h));
    }
    *(uint4*)(hi + ob)     = *(uint4*)hv;
    *(uint4*)(hi + ob + 8) = *(uint4*)(hv + 8);
    *(uint4*)(lo + ob)     = *(uint4*)lv;
    *(uint4*)(lo + ob + 8) = *(uint4*)(lv + 8);
}

// ---------------------------------------------------------------------------
// MFMA QKV GEMM, split-bf16, prefetched + XOR-swizzled LDS.
// Fat M=768 (q/k/v x 2 mtiles), N=9216, K=256. Tile 128x128, BK=32, 4 waves.
// ---------------------------------------------------------------------------
__global__ __launch_bounds__(256) void gemm_qkv_mfma(
    const u16* __restrict__ whi, const u16* __restrict__ wlo,
    const u16* __restrict__ b1hi, const u16* __restrict__ b1lo,
    const u16* __restrict__ b2hi, const u16* __restrict__ b2lo,
    const float* __restrict__ qb, const float* __restrict__ kbias,
    const float* __restrict__ vb, const float* __restrict__ wvis,
    const float* __restrict__ wir, const float* __restrict__ pe,
    float* __restrict__ qo, float* __restrict__ ko, float* __restrict__ vo)
{
    __shared__ uint4 Ah[512], Al[512], Bh[512], Bl[512];  // 4 x 8KB
    int t = threadIdx.x, lane = t & 63;
    int bm = blockIdx.x, bn = blockIdx.y, b = blockIdx.z;
    int mat = bm >> 1, mtile = bm & 1;
    const uint4* gBh = (const uint4*)(((mat == 0) ? b1hi : b2hi) + (size_t)b * PERB + (size_t)bn * 32768);
    const uint4* gBl = (const uint4*)(((mat == 0) ? b1lo : b2lo) + (size_t)b * PERB + (size_t)bn * 32768);
    const uint4* gAh = (const uint4*)(whi + (size_t)(mat * 2 + mtile) * 32768);
    const uint4* gAl = (const uint4*)(wlo + (size_t)(mat * 2 + mtile) * 32768);
    int wv = t >> 6, wm = wv >> 1, wn = wv & 1;
    int rr = lane & 15, gq = lane >> 4;

    // XOR-swizzled LDS slot indices (involution: slot ^= (row>>1)&3)
    int u0 = (t & ~3) | ((t & 3) ^ ((t >> 3) & 3));
    int u1 = u0 + 256;
    int ua[4], ub[4];
#pragma unroll
    for (int f = 0; f < 4; ++f) {
        int rowa = wm * 64 + f * 16 + rr;
        ua[f] = (rowa * 4) | (gq ^ ((rowa >> 1) & 3));
        int rowb = wn * 64 + f * 16 + rr;
        ub[f] = (rowb * 4) | (gq ^ ((rowb >> 1) & 3));
    }

    f32x4 acc[4][4];
#pragma unroll
    for (int i = 0; i < 4; ++i)
#pragma unroll
        for (int j = 0; j < 4; ++j) acc[i][j] = (f32x4){0.f, 0.f, 0.f, 0.f};

    // prefetch tile 0
    uint4 pA0 = gAh[t], pA1 = gAh[t + 256];
    uint4 pB0 = gAl[t], pB1 = gAl[t + 256];
    uint4 pC0 = gBh[t], pC1 = gBh[t + 256];
    uint4 pD0 = gBl[t], pD1 = gBl[t + 256];

    for (int kq = 0; kq < 8; ++kq) {
        __syncthreads();                      // prior reads of LDS done
        Ah[u0] = pA0; Ah[u1] = pA1;
        Al[u0] = pB0; Al[u1] = pB1;
        Bh[u0] = pC0; Bh[u1] = pC1;
        Bl[u0] = pD0; Bl[u1] = pD1;
        __syncthreads();
        if (kq < 7) {                         // issue next-tile loads; wait lands
            const uint4* nah = gAh + (kq + 1) * 512;   // at next iter's LDS writes
            const uint4* nal = gAl + (kq + 1) * 512;
            const uint4* nbh = gBh + (kq + 1) * 512;
            const uint4* nbl = gBl + (kq + 1) * 512;
            pA0 = nah[t]; pA1 = nah[t + 256];
            pB0 = nal[t]; pB1 = nal[t + 256];
            pC0 = nbh[t]; pC1 = nbh[t + 256];
            pD0 = nbl[t]; pD1 = nbl[t + 256];
        }

        short8 bh[4], bl[4];
#pragma unroll
        for (int r = 0; r < 4; ++r) {
            bh[r] = *((const short8*)Bh + ub[r]);
            bl[r] = *((const short8*)Bl + ub[r]);
        }
#pragma unroll
        for (int f = 0; f < 4; ++f) {
            short8 ah = *((const short8*)Ah + ua[f]);
            short8 al = *((const short8*)Al + ua[f]);
#pragma unroll
            for (int r = 0; r < 4; ++r) {
                acc[f][r] = __builtin_amdgcn_mfma_f32_16x16x32_bf16(ah, bh[r], acc[f][r], 0, 0, 0);
                acc[f][r] = __builtin_amdgcn_mfma_f32_16x16x32_bf16(ah, bl[r], acc[f][r], 0, 0, 0);
                acc[f][r] = __builtin_amdgcn_mfma_f32_16x16x32_bf16(al, bh[r], acc[f][r], 0, 0, 0);
            }
        }
    }

    const float* wmap = ((mat == 0) ? wvis : wir) + (size_t)b * NPOS;
    const float* bias = (mat == 0) ? qb : (mat == 1) ? kbias : vb;
    float* outp = ((mat == 0) ? qo : (mat == 1) ? ko : vo) + (size_t)b * PERB;
    bool addpe = (mat != 2);
#pragma unroll
    for (int r = 0; r < 4; ++r) {
        int n = bn * 128 + wn * 64 + r * 16 + rr;
        float sc = wmap[n];
#pragma unroll
        for (int f = 0; f < 4; ++f)
#pragma unroll
            for (int ri = 0; ri < 4; ++ri) {
                int o = mtile * 128 + wm * 64 + f * 16 + gq * 4 + ri;
                float vvv = acc[f][r][ri] * sc + bias[o];
                if (addpe) vvv += pe[(size_t)o * NPOS + n];
                outp[(size_t)o * NPOS + n] = vvv;
            }
    }
}

// ---------------------------------------------------------------------------
// Attention per (b,c): 2-buffer LDS (77KB -> 2 blocks/CU).
// R1 = q then attn; R2 = k then v.
// ---------------------------------------------------------------------------
__global__ __launch_bounds__(256) void attn_kernel(
    const float* __restrict__ q, const float* __restrict__ k,
    const float* __restrict__ v, float* __restrict__ fused)
{
    __shared__ float R1[96 * 100];  // q, later attn
    __shared__ float R2[96 * 100];  // k, later v

    int t  = threadIdx.x;
    int bc = blockIdx.x;
    const size_t base = (size_t)bc * NPOS;

    for (int f = t; f < 96 * 24; f += 256) {
        int r = f / 24, w4 = (f % 24) * 4;
        *(float4*)(R1 + r * 100 + w4) = *(const float4*)(q + base + r * 96 + w4);
        *(float4*)(R2 + r * 100 + w4) = *(const float4*)(k + base + r * 96 + w4);
    }
    __syncthreads();

    int tx = t & 15, ty = t >> 4;
    int h0 = ty * 6, g0 = tx * 6;

    float acc[6][6];
#pragma unroll
    for (int i = 0; i < 6; ++i)
#pragma unroll
        for (int j = 0; j < 6; ++j) acc[i][j] = 0.0f;

    for (int w4 = 0; w4 < 24; ++w4) {
        float4 qv[6], kv[6];
#pragma unroll
        for (int i = 0; i < 6; ++i) qv[i] = *(const float4*)(R1 + (h0 + i) * 100 + w4 * 4);
#pragma unroll
        for (int j = 0; j < 6; ++j) kv[j] = *(const float4*)(R2 + (g0 + j) * 100 + w4 * 4);
#pragma unroll
        for (int i = 0; i < 6; ++i)
#pragma unroll
            for (int j = 0; j < 6; ++j) {
                acc[i][j] = fmaf(qv[i].x, kv[j].x, acc[i][j]);
                acc[i][j] = fmaf(qv[i].y, kv[j].y, acc[i][j]);
                acc[i][j] = fmaf(qv[i].z, kv[j].z, acc[i][j]);
                acc[i][j] = fmaf(qv[i].w, kv[j].w, acc[i][j]);
            }
    }

    // softmax along g (16 lanes sharing ty, wave-internal shuffles)
#pragma unroll
    for (int i = 0; i < 6; ++i) {
        float m = acc[i][0];
#pragma unroll
        for (int j = 1; j < 6; ++j) m = fmaxf(m, acc[i][j]);
        for (int d = 1; d < 16; d <<= 1) m = fmaxf(m, __shfl_xor(m, d));
        float s = 0.0f;
#pragma unroll
        for (int j = 0; j < 6; ++j) {
            acc[i][j] = expf(acc[i][j] - m);
            s += acc[i][j];
        }
        for (int d = 1; d < 16; d <<= 1) s += __shfl_xor(s, d);
        float inv = 1.0f / s;
#pragma unroll
        for (int j = 0; j < 6; ++j) acc[i][j] *= inv;
    }

    __syncthreads();                 // all QK reads of R1/R2 complete
    // attn -> R1; v -> R2 (overwrites q and k)
#pragma unroll
    for (int i = 0; i < 6; ++i)
#pragma unroll
        for (int j = 0; j < 6; ++j) R1[(h0 + i) * 100 + g0 + j] = acc[i][j];
    for (int f = t; f < 96 * 24; f += 256) {
        int r = f / 24, w4 = (f % 24) * 4;
        *(float4*)(R2 + r * 100 + w4) = *(const float4*)(v + base + r * 96 + w4);
    }
    __syncthreads();

    int w0 = tx * 6;
    float outv[6][6];
#pragma unroll
    for (int i = 0; i < 6; ++i)
#pragma unroll
        for (int j = 0; j < 6; ++j) outv[i][j] = 0.0f;

    for (int g4 = 0; g4 < 24; ++g4) {
        float4 av[6];
#pragma unroll
        for (int i = 0; i < 6; ++i) av[i] = *(const float4*)(R1 + (h0 + i) * 100 + g4 * 4);
#pragma unroll
        for (int gg = 0; gg < 4; ++gg) {
            int g = g4 * 4 + gg;
            float vr[6];
#pragma unroll
            for (int j = 0; j < 6; ++j) vr[j] = R2[g * 100 + w0 + j];
#pragma unroll
            for (int i = 0; i < 6; ++i) {
                float a = (gg == 0) ? av[i].x : (gg == 1) ? av[i].y : (gg == 2) ? av[i].z : av[i].w;
#pragma unroll
                for (int j = 0; j < 6; ++j) outv[i][j] = fmaf(a, vr[j], outv[i][j]);
            }
        }
    }

#pragma unroll
    for (int i = 0; i < 6; ++i) {
        float* op = fused + base + (size_t)(h0 + i) * 96 + w0;
#pragma unroll
        for (int j = 0; j < 6; ++j) op[j] = outv[i][j];
    }
}

// ---------------------------------------------------------------------------
// Final projection: out[b][o][n] = sum_c proj_w[o][c]*fused[b][c][n] + pb[o]
// ---------------------------------------------------------------------------
__global__ __launch_bounds__(256) void proj_kernel(
    const float* __restrict__ fused, const float* __restrict__ pw,
    const float* __restrict__ pb, float* __restrict__ out)
{
    __shared__ float As[16 * 68];
    __shared__ float Bs[16 * 128];

    int t  = threadIdx.x;
    int n0 = blockIdx.x * 128;
    int b  = blockIdx.y;
    const float* B = fused + (size_t)b * PERB;
    int tx = t & 15, ty = t >> 4;

    float acc[4][8];
#pragma unroll
    for (int i = 0; i < 4; ++i)
#pragma unroll
        for (int j = 0; j < 8; ++j) acc[i][j] = 0.0f;

    for (int k0 = 0; k0 < 256; k0 += 16) {
        {
            int m = t >> 2, c4 = (t & 3) * 4;
            float4 av = *(const float4*)(pw + (size_t)m * 256 + k0 + c4);
            As[(c4 + 0) * 68 + m] = av.x;
            As[(c4 + 1) * 68 + m] = av.y;
            As[(c4 + 2) * 68 + m] = av.z;
            As[(c4 + 3) * 68 + m] = av.w;
        }
#pragma unroll
        for (int l = 0; l < 2; ++l) {
            int f = t + l * 256;
            int c = f >> 5, n4 = (f & 31) * 4;
            *(float4*)(Bs + c * 128 + n4) =
                *(const float4*)(B + (size_t)(k0 + c) * NPOS + n0 + n4);
        }
        __syncthreads();
#pragma unroll
        for (int kk = 0; kk < 16; ++kk) {
            float a[4], bb[8];
            *(float4*)(&a[0])  = *(const float4*)(As + kk * 68 + ty * 4);
            *(float4*)(&bb[0]) = *(const float4*)(Bs + kk * 128 + tx * 8);
            *(float4*)(&bb[4]) = *(const float4*)(Bs + kk * 128 + tx * 8 + 4);
#pragma unroll
            for (int i = 0; i < 4; ++i)
#pragma unroll
                for (int j = 0; j < 8; ++j)
                    acc[i][j] = fmaf(a[i], bb[j], acc[i][j]);
        }
        __syncthreads();
    }

    int n = n0 + tx * 8;
#pragma unroll
    for (int i = 0; i < 4; ++i) {
        int o = ty * 4 + i;
        float bias = pb[o];
        float vals[8];
#pragma unroll
        for (int j = 0; j < 8; ++j) vals[j] = acc[i][j] + bias;
        float* op = out + ((size_t)b * 64 + o) * NPOS + n;
        *(float4*)(op)     = *(float4*)(&vals[0]);
        *(float4*)(op + 4) = *(float4*)(&vals[4]);
    }
}

// ---------------------------------------------------------------------------
extern "C" void kernel_launch(void* const* d_in, const int* in_sizes, int n_in,
                              void* d_out, int out_size, void* d_ws, size_t ws_size,
                              hipStream_t stream)
{
    const float* x1   = (const float*)d_in[0];
    const float* x2   = (const float*)d_in[1];
    const float* wvis = (const float*)d_in[2];
    const float* wir  = (const float*)d_in[3];
    const float* qw   = (const float*)d_in[4];
    const float* qb   = (const float*)d_in[5];
    const float* kw   = (const float*)d_in[6];
    const float* kb   = (const float*)d_in[7];
    const float* vw   = (const float*)d_in[8];
    const float* vb   = (const float*)d_in[9];
    const float* pw   = (const float*)d_in[10];
    const float* pb   = (const float*)d_in[11];
    float* out = (float*)d_out;

    float* ws = (float*)d_ws;
    size_t F = ws_size / 4;
    size_t fixed = PERB + 600000;
    size_t avail = (F > fixed) ? (F - fixed) : 0;
    int G = (int)(avail / (6 * PERB));
    if (G < 1) G = 1;
    if (G > 8) G = 8;

    float* pebuf = ws;
    float* qbuf  = ws + PERB;
    float* kbuf  = qbuf + (size_t)G * PERB;
    float* vbuf  = kbuf + (size_t)G * PERB;
    float* fbuf  = vbuf + (size_t)G * PERB;
    u16*   b1hi  = (u16*)(fbuf + (size_t)G * PERB);
    u16*   b1lo  = b1hi + (size_t)G * PERB;
    u16*   b2hi  = b1lo + (size_t)G * PERB;
    u16*   b2lo  = b2hi + (size_t)G * PERB;
    u16*   whiP  = b2lo + (size_t)G * PERB;
    u16*   wloP  = whiP + 589824;

    pe_kernel<<<dim3(36, 64), 256, 0, stream>>>(pebuf);
    wsplit<<<dim3(144), 256, 0, stream>>>(qw, kw, vw, whiP, wloP);

    for (int b0 = 0; b0 < 16; b0 += G) {
        int g = (16 - b0 < G) ? (16 - b0) : G;
        splitcvt<<<dim3(576, g), 256, 0, stream>>>(x1 + (size_t)b0 * PERB, b1hi, b1lo);
        splitcvt<<<dim3(576, g), 256, 0, stream>>>(x2 + (size_t)b0 * PERB, b2hi, b2lo);
        for (int s = 0; s < 3; ++s) {
            if (s > 0)
                splitcvt<<<dim3(576, g), 256, 0, stream>>>(fbuf, b1hi, b1lo);
            const u16* xh = (s == 0) ? b2hi : b1hi;
            const u16* xl = (s == 0) ? b2lo : b1lo;
            gemm_qkv_mfma<<<dim3(6, 72, g), 256, 0, stream>>>(
                whiP + (size_t)s * 196608, wloP + (size_t)s * 196608,
                b1hi, b1lo, xh, xl,
                qb + (size_t)s * 256, kb + (size_t)s * 256, vb + (size_t)s * 256,
                wvis + (size_t)b0 * NPOS, wir + (size_t)b0 * NPOS,
                pebuf, qbuf, kbuf, vbuf);
            attn_kernel<<<dim3(256 * g), 256, 0, stream>>>(qbuf, kbuf, vbuf, fbuf);
        }
        proj_kernel<<<dim3(72, g), 256, 0, stream>>>(
            fbuf, pw, pb, out + (size_t)b0 * 64 * NPOS);
    }
}